// Round 11
// baseline (110.739 us; speedup 1.0000x reference)
//
#include <hip/hip_runtime.h>

// SSIM loss, wave-autonomous + register ring buffer. B=32, H=W=512, win=11.
// R11: instruction-count attack on the R10 geometry (920 blocks, 5 strips x
// 23 bands x 22 rows, guard-free): scan-based hwin (15 vs 18 instrs, chain 6
// vs 10), float2-packed vertical/SSIM math (v_pk_fma_f32), unroll-1 outer
// loop (small I-footprint), TAIL-templated band so interior bands have no
// per-iter clamps/compares. Math identical to verified rounds (absmax 0).

#define WW 512
#define OH 502
#define BANDR 22
#define NBANDS 23
#define INV_N (1.0f / 8064128.0f)   // 32*502*502

#define DPP_ADD(x, ctrl, rmask)                                            \
    x += __int_as_float(__builtin_amdgcn_update_dpp(                       \
        0, __float_as_int(x), (ctrl), (rmask), 0xf, true))

__device__ __forceinline__ float wave_iscan(float x) {
    DPP_ADD(x, 0x111, 0xf);   // row_shr:1
    DPP_ADD(x, 0x112, 0xf);   // row_shr:2
    DPP_ADD(x, 0x114, 0xf);   // row_shr:4
    DPP_ADD(x, 0x118, 0xf);   // row_shr:8
    DPP_ADD(x, 0x142, 0xa);   // row_bcast:15 -> rows 1,3
    DPP_ADD(x, 0x143, 0xc);   // row_bcast:31 -> rows 2,3
    return x;
}

// 11-tap horizontal window sums for this lane's two columns (2l, 2l+1).
// Verified exact in R4 (absmax 0.0).
__device__ __forceinline__ float2 hwin(float v0, float v1, int lane) {
    float e = v0 + v1;            // pair sum
    float S = wave_iscan(e);      // inclusive scan over pairs
    float A4 = __shfl(S, lane + 4);
    float A5 = __shfl(S, lane + 5);
    float v5 = __shfl(v0, lane + 5);
    float W0 = A4 - S + e + v5;   // cols 2l .. 2l+10
    float W1 = A5 - S + v1;       // cols 2l+1 .. 2l+11
    return make_float2(W0, W1);
}

// float2 packed-math helpers (target v_pk_add_f32 / v_pk_fma_f32)
__device__ __forceinline__ float2 f2add(float2 a, float2 b){ return make_float2(a.x+b.x, a.y+b.y); }
__device__ __forceinline__ float2 f2sub(float2 a, float2 b){ return make_float2(a.x-b.x, a.y-b.y); }
__device__ __forceinline__ float2 f2mul(float2 a, float2 b){ return make_float2(a.x*b.x, a.y*b.y); }
__device__ __forceinline__ float2 f2fma(float2 a, float2 b, float2 c){
    return make_float2(fmaf(a.x,b.x,c.x), fmaf(a.y,b.y,c.y)); }
__device__ __forceinline__ float2 f2fms(float2 a, float2 b, float2 c){   // a*b - c
    return make_float2(fmaf(a.x,b.x,-c.x), fmaf(a.y,b.y,-c.y)); }
__device__ __forceinline__ float2 f2nfma(float2 a, float2 b, float2 c){  // c - a*b
    return make_float2(fmaf(-a.x,b.x,c.x), fmaf(-a.y,b.y,c.y)); }

// SSIM for the lane's two columns, packed; masked accumulate value.
__device__ __forceinline__ float ssim2(float2 w0, float2 w1, float2 w2, float2 w3,
                                       bool valid) {
    const float NP = 121.f, cn = 121.f/120.f;
    const float2 C1n = make_float2(1e-4f*121.f*121.f, 1e-4f*121.f*121.f);
    const float2 C2n = make_float2(9e-4f*121.f*121.f, 9e-4f*121.f*121.f);
    const float2 NP2 = make_float2(NP, NP);
    float2 m1 = f2mul(w0, w1);
    float2 q1 = f2fma(w0, w0, f2mul(w1, w1));
    float2 A1 = f2fma(make_float2(2.f,2.f), m1, C1n);
    float2 B1 = f2add(q1, C1n);
    float2 A2 = f2fma(make_float2(2.f*cn,2.f*cn), f2fms(NP2, w3, m1), C2n);
    float2 B2 = f2fma(make_float2(cn,cn), f2fms(NP2, w2, q1), C2n);
    float2 num = f2mul(A1, A2), den = f2mul(B1, B2);
    float r = fmaf(num.x, __builtin_amdgcn_rcpf(den.x),
                   num.y * __builtin_amdgcn_rcpf(den.y));
    return valid ? r : 0.f;
}

template<bool TAIL>
__device__ __forceinline__ float run_band(const float* __restrict__ Pc0,
                                          const float* __restrict__ Tc0,
                                          int y0, int lane, bool ok) {
    float2 prr[11], trr[11];
    float2 sp = make_float2(0,0), st = make_float2(0,0);
    float2 sq = make_float2(0,0), sx = make_float2(0,0);

    // prime: rows y0..y0+9 into ring slots 0..9
    #pragma unroll
    for (int r = 0; r < 10; ++r) {
        float2 p = *(const float2*)(Pc0 + (y0 + r) * WW);
        float2 t = *(const float2*)(Tc0 + (y0 + r) * WW);
        prr[r] = p; trr[r] = t;
        sp = f2add(sp, p); st = f2add(st, t);
        sq = f2fma(p, p, sq); sq = f2fma(t, t, sq);
        sx = f2fma(p, t, sx);
    }
    // depth-3 prefetch: rows y0+10..y0+12 (always <512 even for tail band)
    float2 Pn0 = *(const float2*)(Pc0 + (y0 + 10) * WW);
    float2 Tn0 = *(const float2*)(Tc0 + (y0 + 10) * WW);
    float2 Pn1 = *(const float2*)(Pc0 + (y0 + 11) * WW);
    float2 Tn1 = *(const float2*)(Tc0 + (y0 + 11) * WW);
    float2 Pn2 = *(const float2*)(Pc0 + (y0 + 12) * WW);
    float2 Tn2 = *(const float2*)(Tc0 + (y0 + 12) * WW);

    float acc = 0.f;

    #pragma unroll 1
    for (int blk = 0; blk < 2; ++blk) {          // 2 x 11 rows, straight-line
        #pragma unroll
        for (int j = 0; j < 11; ++j) {
            const int sn = (10 + j) % 11;        // static ring slot
            const int y  = y0 + 11 * blk + j;
            float2 Pc = Pn0, Tc = Tn0;
            Pn0 = Pn1; Tn0 = Tn1;
            Pn1 = Pn2; Tn1 = Tn2;
            const int nr = TAIL ? min(y + 13, 511) : (y + 13);
            Pn2 = *(const float2*)(Pc0 + nr * WW);
            Tn2 = *(const float2*)(Tc0 + nr * WW);
            prr[sn] = Pc; trr[sn] = Tc;
            sp = f2add(sp, Pc); st = f2add(st, Tc);
            sq = f2fma(Pc, Pc, sq); sq = f2fma(Tc, Tc, sq);
            sx = f2fma(Pc, Tc, sx);
            float2 w0 = hwin(sp.x, sp.y, lane);
            float2 w1 = hwin(st.x, st.y, lane);
            float2 w2 = hwin(sq.x, sq.y, lane);
            float2 w3 = hwin(sx.x, sx.y, lane);
            const bool valid = ok && (!TAIL || y < OH);
            acc += ssim2(w0, w1, w2, w3, valid);
            float2 po = prr[j], to = trr[j];
            sp = f2sub(sp, po); st = f2sub(st, to);
            sq = f2nfma(po, po, sq); sq = f2nfma(to, to, sq);
            sx = f2nfma(po, to, sx);
        }
    }
    return acc;
}

__global__ __launch_bounds__(256)
void ssim_main(const float* __restrict__ Pg, const float* __restrict__ Tg,
               float* __restrict__ outp) {
    const int tid  = threadIdx.x;
    const int lane = tid & 63;
    const int wv   = tid >> 6;
    const int Wid  = blockIdx.x * 4 + wv;      // 0..3679
    const int img   = Wid / 115;               // 5 strips * 23 bands
    const int rem   = Wid - img * 115;
    const int strip = rem / NBANDS;
    const int band  = rem - strip * NBANDS;

    const int col0 = (strip == 4) ? 472 : strip * 118;
    const int outw = (strip == 4) ? 30 : 118;
    const int y0   = band * BANDR;             // band 22: 484

    const int cload = min(col0 + 2 * lane, 510);
    const bool ok   = lane < (outw >> 1);

    const float* Pc0 = Pg + img * (WW * WW) + cload;
    const float* Tc0 = Tg + img * (WW * WW) + cload;

    float acc;
    if (band == NBANDS - 1)
        acc = run_band<true >(Pc0, Tc0, y0, lane, ok);
    else
        acc = run_band<false>(Pc0, Tc0, y0, lane, ok);

    // ---- reduce: wave -> block -> one atomicAdd ----
    #pragma unroll
    for (int off = 32; off > 0; off >>= 1) acc += __shfl_down(acc, off);
    __shared__ float wred[4];
    if (lane == 0) wred[wv] = acc;
    __syncthreads();
    if (tid == 0) {
        float s = wred[0] + wred[1] + wred[2] + wred[3];
        float contrib = -s * INV_N;
        if (blockIdx.x == 0) contrib += 1.0f;
        atomicAdd(outp, contrib);
    }
}

extern "C" void kernel_launch(void* const* d_in, const int* in_sizes, int n_in,
                              void* d_out, int out_size, void* d_ws, size_t ws_size,
                              hipStream_t stream) {
    const float* pred = (const float*)d_in[0];
    const float* targ = (const float*)d_in[1];
    float* out = (float*)d_out;

    hipMemsetAsync(out, 0, sizeof(float), stream);
    ssim_main<<<dim3(920), dim3(256), 0, stream>>>(pred, targ, out);
}